// Round 8
// baseline (226.407 us; speedup 1.0000x reference)
//
#include <hip/hip_runtime.h>

// Problem constants
#define BATCH 2
#define NSEQ 2304       // 48*48
#define DIM 768
#define HEADS 12
#define HD 64
#define M_TOK (BATCH * NSEQ)   // 4608
#define LDSP 72                // padded LDS row stride (bf16 elems)
#define KP 72                  // attn LDS row stride (elems) for K (bf16) and V^T (f16)
#define BH (BATCH * HEADS)     // 24
#define KT_HALF (NSEQ / 64 / 2) // 18 key-tiles per half

typedef __attribute__((ext_vector_type(8))) short bf16x8;
typedef __attribute__((ext_vector_type(8))) short short8v;
typedef __attribute__((ext_vector_type(4))) float f32x4;
typedef __fp16 fp16x2 __attribute__((ext_vector_type(2)));
typedef _Float16 half4 __attribute__((ext_vector_type(4)));
typedef _Float16 half8 __attribute__((ext_vector_type(8)));

// softmax scale folded with log2(e): exp(x) = exp2(x * log2e)
#define QSCALE (0.125f * 1.44269504088896f)
#define LOG2_100_D16 0.41524101186092029f   // log2(100)/16

__device__ __forceinline__ short f2bf(float f) {
    union { float f; unsigned u; } v; v.f = f;
    unsigned r = v.u + 0x7fffu + ((v.u >> 16) & 1u);
    return (short)(r >> 16);
}

// ---------------- merged fp32 -> bf16 conversion for x, w_qkv, w_proj ----------------
#define CN1 (M_TOK * DIM / 4)        // 884736
#define CN2 (3 * DIM * DIM / 4)      // 442368
#define CN3 (DIM * DIM / 4)          // 147456
__global__ void cvt_all_kernel(const float* __restrict__ x, const float* __restrict__ wq,
                               const float* __restrict__ wp,
                               short* __restrict__ xb, short* __restrict__ wqb,
                               short* __restrict__ wpb) {
    int i = blockIdx.x * 256 + threadIdx.x;
    const float* src; short* dst; int j;
    if (i < CN1)              { src = x;  dst = xb;  j = i; }
    else if (i < CN1 + CN2)   { src = wq; dst = wqb; j = i - CN1; }
    else                      { src = wp; dst = wpb; j = i - CN1 - CN2; }
    float4 v = reinterpret_cast<const float4*>(src)[j];
    short4 o;
    o.x = f2bf(v.x); o.y = f2bf(v.y); o.z = f2bf(v.z); o.w = f2bf(v.w);
    reinterpret_cast<short4*>(dst)[j] = o;
}

// ---------------- qkv GEMM: 128x128 tile, 2-deep prefetch pipeline ----------------
// R8: R7's pipeline was correct but SPILLED: staging needs ~152 VGPRs, compiler held
// 88 (default 4-waves/SIMD target) -> 220 MB scratch WRITE_SIZE. LDS already caps
// occupancy at 2 blocks/CU, so declare it: __launch_bounds__(256, 2) -> 256-reg
// budget, staging stays in registers. Pipeline: at tile t, ds_write regs loaded one
// FULL iteration ago (latency drained), issue loads for t+2, compute t.
__device__ __forceinline__ void qkv_load(const short* __restrict__ A,
                                         const short* __restrict__ Bt,
                                         int m0, int n0, int r, int c0, int koff,
                                         uint4 (&ra)[4], uint4 (&rb)[4]) {
    const uint4* ga = reinterpret_cast<const uint4*>(&A[(size_t)(m0 + r) * DIM + koff + c0]);
    const uint4* gb = reinterpret_cast<const uint4*>(&Bt[(size_t)(n0 + r) * DIM + koff + c0]);
    ra[0] = ga[0]; ra[1] = ga[1]; ra[2] = ga[2]; ra[3] = ga[3];
    rb[0] = gb[0]; rb[1] = gb[1]; rb[2] = gb[2]; rb[3] = gb[3];
}

__device__ __forceinline__ void qkv_store(short* At, short* Bl, int r, int c0,
                                          const uint4 (&ra)[4], const uint4 (&rb)[4]) {
    uint4* sa = reinterpret_cast<uint4*>(&At[r * LDSP + c0]);
    uint4* sb = reinterpret_cast<uint4*>(&Bl[r * LDSP + c0]);
    sa[0] = ra[0]; sa[1] = ra[1]; sa[2] = ra[2]; sa[3] = ra[3];
    sb[0] = rb[0]; sb[1] = rb[1]; sb[2] = rb[2]; sb[3] = rb[3];
}

__device__ __forceinline__ void qkv_compute(const short* At, const short* Bl,
                                            int wm, int wn, int l16, int quad,
                                            f32x4 (&acc)[4][4]) {
#pragma unroll
    for (int ks = 0; ks < 2; ++ks) {
        bf16x8 af[4], bf[4];
#pragma unroll
        for (int mt = 0; mt < 4; ++mt)
            af[mt] = *reinterpret_cast<const bf16x8*>(&At[(wm + mt * 16 + l16) * LDSP + ks * 32 + quad * 8]);
#pragma unroll
        for (int nt = 0; nt < 4; ++nt)
            bf[nt] = *reinterpret_cast<const bf16x8*>(&Bl[(wn + nt * 16 + l16) * LDSP + ks * 32 + quad * 8]);
#pragma unroll
        for (int mt = 0; mt < 4; ++mt)
#pragma unroll
            for (int nt = 0; nt < 4; ++nt)
                acc[mt][nt] = __builtin_amdgcn_mfma_f32_16x16x32_bf16(af[mt], bf[nt], acc[mt][nt], 0, 0, 0);
    }
}

__global__ __launch_bounds__(256, 2) void gemm_qkv_kernel(
    const short* __restrict__ A,    // xb [4608,768]
    const short* __restrict__ Bt,   // wqkvb [2304,768]
    const float* __restrict__ bias, // [2304]
    short* __restrict__ qb, short* __restrict__ kbuf, _Float16* __restrict__ vtb)
{
    __shared__ __align__(16) short At[2][128 * LDSP];
    __shared__ __align__(16) short Bl[2][128 * LDSP];
    const int m0 = blockIdx.x * 128, n0 = blockIdx.y * 128;
    const int tid = threadIdx.x, lane = tid & 63, wave = tid >> 6;
    const int quad = lane >> 4, l16 = lane & 15;
    const int wm = (wave >> 1) * 64, wn = (wave & 1) * 64;
    const int r = tid >> 1, c0 = (tid & 1) * 32;
    f32x4 acc[4][4] = {};

    uint4 rA1[4], rB1[4], rA2[4], rB2[4];

    // prologue: tile 0 -> buf0 (direct), tile 1 -> reg set 1 (in flight)
    qkv_load(A, Bt, m0, n0, r, c0, 0, rA1, rB1);
    qkv_store(At[0], Bl[0], r, c0, rA1, rB1);
    qkv_load(A, Bt, m0, n0, r, c0, 64, rA1, rB1);

    // even tiles live in buf0, odd tiles in buf1
#pragma unroll
    for (int j = 0; j < 6; ++j) {
        const int t = 2 * j;
        __syncthreads();                                    // buf0(tile t) visible
        qkv_store(At[1], Bl[1], r, c0, rA1, rB1);           // tile t+1 (loaded 1 iter ago)
        if (j < 5) qkv_load(A, Bt, m0, n0, r, c0, (t + 2) * 64, rA2, rB2);
        qkv_compute(At[0], Bl[0], wm, wn, l16, quad, acc);  // tile t

        __syncthreads();                                    // buf1(tile t+1) visible
        if (j < 5) qkv_store(At[0], Bl[0], r, c0, rA2, rB2);// tile t+2
        if (j < 5) qkv_load(A, Bt, m0, n0, r, c0, (t + 3) * 64, rA1, rB1);
        qkv_compute(At[1], Bl[1], wm, wn, l16, quad, acc);  // tile t+1
    }

    const int which = (n0 + wn) / DIM;          // 0=q 1=k 2=v (wave-uniform)
    const int head = ((n0 + wn) % DIM) / HD;
    const int b = m0 / NSEQ;
    const int tokb = m0 % NSEQ + wm;
    if (which == 2) {
#pragma unroll
        for (int mt = 0; mt < 4; ++mt)
#pragma unroll
            for (int nt = 0; nt < 4; ++nt) {
                const int n = n0 + wn + nt * 16 + l16;
                const int d = nt * 16 + l16;
                const float bi = bias[n];
                const int tok0 = tokb + mt * 16 + quad * 4;
                half4 hv;
                hv.x = (_Float16)(acc[mt][nt][0] + bi);
                hv.y = (_Float16)(acc[mt][nt][1] + bi);
                hv.z = (_Float16)(acc[mt][nt][2] + bi);
                hv.w = (_Float16)(acc[mt][nt][3] + bi);
                *reinterpret_cast<half4*>(&vtb[((size_t)(b * HEADS + head) * HD + d) * NSEQ + tok0]) = hv;
            }
    } else {
        // fused RoPE: pairs (d, d+32) = (nt, nt+2); pi = l16
        short* dst = (which == 0) ? qb : kbuf;
        const float qs = (which == 0) ? QSCALE : 1.0f;
        float bi[4];
#pragma unroll
        for (int nt = 0; nt < 4; ++nt) bi[nt] = bias[n0 + wn + nt * 16 + l16];
        const float invp = __builtin_amdgcn_exp2f(-(float)l16 * LOG2_100_D16); // 100^(-l16/16)
#pragma unroll
        for (int mt = 0; mt < 4; ++mt) {
#pragma unroll
            for (int rg = 0; rg < 4; ++rg) {
                const int tok = tokb + mt * 16 + quad * 4 + rg;
                const int yy = tok / 48, xx = tok - yy * 48;
                const float ry = (2.0f * (yy + 0.5f) * (1.0f / 48.0f) - 1.0f) * invp; // revolutions
                const float rx = (2.0f * (xx + 0.5f) * (1.0f / 48.0f) - 1.0f) * invp;
                const float sy = __builtin_amdgcn_sinf(ry), cy = __builtin_amdgcn_cosf(ry);
                const float sx = __builtin_amdgcn_sinf(rx), cx = __builtin_amdgcn_cosf(rx);
                const float a0 = acc[mt][0][rg] + bi[0];
                const float a1 = acc[mt][1][rg] + bi[1];
                const float a2 = acc[mt][2][rg] + bi[2];
                const float a3 = acc[mt][3][rg] + bi[3];
                short* rp = &dst[((size_t)(b * HEADS + head) * NSEQ + tok) * HD];
                rp[l16]      = f2bf((a0 * cy - a2 * sy) * qs);
                rp[32 + l16] = f2bf((a2 * cy + a0 * sy) * qs);
                rp[16 + l16] = f2bf((a1 * cx - a3 * sx) * qs);
                rp[48 + l16] = f2bf((a3 * cx + a1 * sx) * qs);
            }
        }
    }
}

// ---------------- flash attention: 8 waves x 32 q-rows, key-split x2, XCD-swizzled ----------------
// R6 structure (kept): <=128-reg tier -> 4 waves/SIMD; 512-thread blocks, 256 rows.
// K/V LDS layouts conflict-uniform b128 (R4).
__global__ __launch_bounds__(512, 4) void attn_kernel(
    const short* __restrict__ qb, const short* __restrict__ kb,
    const _Float16* __restrict__ vtb, _Float16* __restrict__ opart,
    float* __restrict__ lpart)
{
    __shared__ __align__(16) short    Kt[2][64 * KP];   // [key][d]        bf16
    __shared__ __align__(16) _Float16 Vt[2][64 * KP];   // [d][tok-perm]   f16
    const int wg = blockIdx.x;
    const int xcd = wg & 7;
    const int slot = wg >> 3;              // 0..53
    const int slab = xcd * 6 + slot / 9;   // 0..47 (all 9 q-tiles of a slab on one XCD)
    const int qt = slot % 9;
    const int kh = slab & 1;
    const int bh = slab >> 1;
    const int tid = threadIdx.x, lane = tid & 63, wave = tid >> 6;   // wave 0..7
    const int quad = lane >> 4, l16 = lane & 15;
    const int qrow0 = qt * 256 + wave * 32;
    const short* qbase = qb + (size_t)bh * NSEQ * HD;
    const short* kbase = kb + (size_t)bh * NSEQ * HD;
    const _Float16* vbase = vtb + (size_t)bh * HD * NSEQ;

    bf16x8 qf[2][2];
#pragma unroll
    for (int mt = 0; mt < 2; ++mt)
#pragma unroll
        for (int ks = 0; ks < 2; ++ks)
            qf[mt][ks] = *reinterpret_cast<const bf16x8*>(
                &qbase[(size_t)(qrow0 + mt * 16 + l16) * HD + ks * 32 + quad * 8]);

    half8 ones8;
#pragma unroll
    for (int j = 0; j < 8; ++j) ones8[j] = (_Float16)1.0f;

    f32x4 oacc[2][4] = {};
    f32x4 lacc[2] = {};

    // staging (512 threads, one uint4 each):
    //   K: row rk = tid>>3, 8 shorts at ck = (tid&7)*8
    //   V: d-row rv = tid>>3, 8 tokens T = 8*(tid&7); permuted dest
    //      p0 = 32*(w>>2) + 16*(w&1) + 4*((w>>1)&1)  [uint2 at p0, p0+8]
    const int rk = tid >> 3, ck = (tid & 7) * 8;
    const int wv = tid & 7;
    const int vdst = rk * KP + 32 * (wv >> 2) + 16 * (wv & 1) + 4 * ((wv >> 1) & 1);
    const int t0 = kh * (NSEQ / 2);
    const short* kp = kbase + (size_t)(t0 + rk) * HD + ck;
    const _Float16* vp = vbase + (size_t)rk * NSEQ + t0 + wv * 8;

    // prologue: stage first tile into buffer 0
    {
        uint4 k0 = *reinterpret_cast<const uint4*>(kp);
        uint4 v0 = *reinterpret_cast<const uint4*>(vp);
        *reinterpret_cast<uint4*>(&Kt[0][rk * KP + ck]) = k0;
        _Float16* vb = &Vt[0][vdst];
        *reinterpret_cast<uint2*>(vb + 0) = make_uint2(v0.x, v0.y);
        *reinterpret_cast<uint2*>(vb + 8) = make_uint2(v0.z, v0.w);
        kp += 64 * HD;
        vp += 64;
    }

    int cur = 0;
    for (int kt = 0; kt < KT_HALF; ++kt) {
        __syncthreads();   // buf[cur] visible; readers of buf[cur^1] done
        uint4 k0, v0;
        const bool pre = (kt + 1 < KT_HALF);
        if (pre) {   // issue next-tile loads; latency hides under this tile's compute
            k0 = *reinterpret_cast<const uint4*>(kp);
            v0 = *reinterpret_cast<const uint4*>(vp);
            kp += 64 * HD;
            vp += 64;
        }

        // hoist K and V^T fragments once, reuse over 2 m-tiles (all b128, conflict-uniform)
        bf16x8 kf[2][4];
#pragma unroll
        for (int ks = 0; ks < 2; ++ks)
#pragma unroll
            for (int nt = 0; nt < 4; ++nt)
                kf[ks][nt] = *reinterpret_cast<const bf16x8*>(
                    &Kt[cur][(nt * 16 + l16) * KP + ks * 32 + quad * 8]);
        half8 vf8[2][4];
#pragma unroll
        for (int n2 = 0; n2 < 2; ++n2)
#pragma unroll
            for (int dt = 0; dt < 4; ++dt)
                vf8[n2][dt] = *reinterpret_cast<const half8*>(
                    &Vt[cur][(dt * 16 + l16) * KP + 32 * n2 + 8 * quad]);

#pragma unroll
        for (int mt = 0; mt < 2; ++mt) {
            // S^T = K Q^T for this 16-row m-tile
            f32x4 sacc[4] = {};
#pragma unroll
            for (int ks = 0; ks < 2; ++ks)
#pragma unroll
                for (int nt = 0; nt < 4; ++nt)
                    sacc[nt] = __builtin_amdgcn_mfma_f32_16x16x32_bf16(
                        kf[ks][nt], qf[mt][ks], sacc[nt], 0, 0, 0);

            // P = exp2(S^T) -> K=32 f16 A-fragments (key-permuted, matches vf8)
            half8 pf8[2];
#pragma unroll
            for (int n2 = 0; n2 < 2; ++n2) {
                fp16x2 w0 = __builtin_amdgcn_cvt_pkrtz(
                    __builtin_amdgcn_exp2f(sacc[2 * n2][0]),
                    __builtin_amdgcn_exp2f(sacc[2 * n2][1]));
                fp16x2 w1 = __builtin_amdgcn_cvt_pkrtz(
                    __builtin_amdgcn_exp2f(sacc[2 * n2][2]),
                    __builtin_amdgcn_exp2f(sacc[2 * n2][3]));
                fp16x2 w2 = __builtin_amdgcn_cvt_pkrtz(
                    __builtin_amdgcn_exp2f(sacc[2 * n2 + 1][0]),
                    __builtin_amdgcn_exp2f(sacc[2 * n2 + 1][1]));
                fp16x2 w3 = __builtin_amdgcn_cvt_pkrtz(
                    __builtin_amdgcn_exp2f(sacc[2 * n2 + 1][2]),
                    __builtin_amdgcn_exp2f(sacc[2 * n2 + 1][3]));
                half8 p;
                p[0] = (_Float16)w0.x; p[1] = (_Float16)w0.y;
                p[2] = (_Float16)w1.x; p[3] = (_Float16)w1.y;
                p[4] = (_Float16)w2.x; p[5] = (_Float16)w2.y;
                p[6] = (_Float16)w3.x; p[7] = (_Float16)w3.y;
                pf8[n2] = p;
            }

            // l += P * ones ; O += P V   (K=32 f16 MFMAs)
#pragma unroll
            for (int n2 = 0; n2 < 2; ++n2)
                lacc[mt] = __builtin_amdgcn_mfma_f32_16x16x32_f16(
                    pf8[n2], ones8, lacc[mt], 0, 0, 0);
#pragma unroll
            for (int n2 = 0; n2 < 2; ++n2)
#pragma unroll
                for (int dt = 0; dt < 4; ++dt)
                    oacc[mt][dt] = __builtin_amdgcn_mfma_f32_16x16x32_f16(
                        pf8[n2], vf8[n2][dt], oacc[mt][dt], 0, 0, 0);
        }

        if (pre) {   // stage next tile; vmcnt wait lands after the tile's compute
            *reinterpret_cast<uint4*>(&Kt[cur ^ 1][rk * KP + ck]) = k0;
            _Float16* vb = &Vt[cur ^ 1][vdst];
            *reinterpret_cast<uint2*>(vb + 0) = make_uint2(v0.x, v0.y);
            *reinterpret_cast<uint2*>(vb + 8) = make_uint2(v0.z, v0.w);
        }
        cur ^= 1;
    }

    // store UNNORMALIZED partials
    _Float16* ob2 = opart + (size_t)(kh * BH + bh) * NSEQ * HD;
    float* lp2 = lpart + (size_t)(kh * BH + bh) * NSEQ;
#pragma unroll
    for (int mt = 0; mt < 2; ++mt) {
#pragma unroll
        for (int dt = 0; dt < 4; ++dt)
#pragma unroll
            for (int rg = 0; rg < 4; ++rg) {
                int row = qrow0 + mt * 16 + quad * 4 + rg;
                ob2[(size_t)row * HD + dt * 16 + l16] = (_Float16)oacc[mt][dt][rg];
            }
        if (l16 == 0) {
#pragma unroll
            for (int rg = 0; rg < 4; ++rg)
                lp2[qrow0 + mt * 16 + quad * 4 + rg] = lacc[mt][rg];
        }
    }
}

// ---------------- proj GEMM with fused softmax-combine ----------------
__global__ __launch_bounds__(256) void gemm_proj_kernel(
    const _Float16* __restrict__ op,  // [2][bh][row][d] f16 partials
    const float* __restrict__ lp,     // [2][bh][row] f32 partials
    const short* __restrict__ Bt,     // wprojb [768,768]
    const float* __restrict__ bias,   // [768]
    float* __restrict__ out)
{
    __shared__ __align__(16) short At[64 * LDSP];
    __shared__ __align__(16) short Bl[64 * LDSP];
    const int m0 = blockIdx.x * 64, n0 = blockIdx.y * 64;
    const int tid = threadIdx.x, lane = tid & 63, wave = tid >> 6;
    const int quad = lane >> 4, l16 = lane & 15;
    const int wm = (wave >> 1) * 32, wn = (wave & 1) * 32;
    const int r = tid >> 2, cs = (tid & 3) * 16;
    const int b = m0 / NSEQ;
    const int tok = m0 % NSEQ + r;
    f32x4 acc[2][2] = {};

    for (int k0 = 0; k0 < DIM; k0 += 64) {
        // fused combine: this k-tile is head h
        const int h = k0 >> 6;
        const size_t pb = (size_t)(b * HEADS + h) * NSEQ + tok;
        const float l0 = lp[pb], l1 = lp[(size_t)BH * NSEQ + pb];
        const float inv = __builtin_amdgcn_rcpf(l0 + l1);
        const half8* o0 = reinterpret_cast<const half8*>(&op[pb * HD + cs]);
        const half8* o1 = reinterpret_cast<const half8*>(&op[(size_t)BH * NSEQ * HD + pb * HD + cs]);
        half8 p0 = o0[0], p1 = o0[1], q0 = o1[0], q1 = o1[1];
        const uint4* gb = reinterpret_cast<const uint4*>(&Bt[(size_t)(n0 + r) * DIM + k0 + cs]);
        uint4 bw0 = gb[0], bw1 = gb[1];
        short8v s0, s1;
#pragma unroll
        for (int j = 0; j < 8; ++j) {
            s0[j] = f2bf(((float)p0[j] + (float)q0[j]) * inv);
            s1[j] = f2bf(((float)p1[j] + (float)q1[j]) * inv);
        }
        *reinterpret_cast<short8v*>(&At[r * LDSP + cs]) = s0;
        *reinterpret_cast<short8v*>(&At[r * LDSP + cs + 8]) = s1;
        uint4* sb = reinterpret_cast<uint4*>(&Bl[r * LDSP + cs]);
        sb[0] = bw0; sb[1] = bw1;
        __syncthreads();
#pragma unroll
        for (int ks = 0; ks < 2; ++ks) {
            bf16x8 af[2], bf[2];
#pragma unroll
            for (int mt = 0; mt < 2; ++mt)
                af[mt] = *reinterpret_cast<const bf16x8*>(&At[(wm + mt * 16 + l16) * LDSP + ks * 32 + quad * 8]);
#pragma unroll
            for (int nt = 0; nt < 2; ++nt)
                bf[nt] = *reinterpret_cast<const bf16x8*>(&Bl[(wn + nt * 16 + l16) * LDSP + ks * 32 + quad * 8]);
#pragma unroll
            for (int mt = 0; mt < 2; ++mt)
#pragma unroll
                for (int nt = 0; nt < 2; ++nt)
                    acc[mt][nt] = __builtin_amdgcn_mfma_f32_16x16x32_bf16(af[mt], bf[nt], acc[mt][nt], 0, 0, 0);
        }
        __syncthreads();
    }

#pragma unroll
    for (int mt = 0; mt < 2; ++mt)
#pragma unroll
        for (int nt = 0; nt < 2; ++nt) {
            const int n = n0 + wn + nt * 16 + l16;
            const float bi = bias[n];
#pragma unroll
            for (int rg = 0; rg < 4; ++rg) {
                const int m = m0 + wm + mt * 16 + quad * 4 + rg;
                out[(size_t)m * DIM + n] = acc[mt][nt][rg] + bi;
            }
        }
}

extern "C" void kernel_launch(void* const* d_in, const int* in_sizes, int n_in,
                              void* d_out, int out_size, void* d_ws, size_t ws_size,
                              hipStream_t stream) {
    const float* x      = (const float*)d_in[0];
    const float* w_qkv  = (const float*)d_in[1];
    const float* b_qkv  = (const float*)d_in[2];
    const float* w_proj = (const float*)d_in[3];
    const float* b_proj = (const float*)d_in[4];
    float* out = (float*)d_out;

    short* xb     = (short*)d_ws;                         // 4608*768
    short* wqkvb  = xb + (size_t)M_TOK * DIM;             // 2304*768
    short* wprojb = wqkvb + (size_t)3 * DIM * DIM;        // 768*768
    short* qb     = wprojb + (size_t)DIM * DIM;           // 24*2304*64 bf16
    short* kb     = qb + (size_t)BH * NSEQ * HD;
    short* vtb    = kb + (size_t)BH * NSEQ * HD;          // f16 [bh,d,tok]
    short* opart  = vtb + (size_t)BH * NSEQ * HD;         // f16 [2,bh,row,d]
    float* lpart  = (float*)(opart + (size_t)2 * BH * NSEQ * HD); // f32 [2,bh,row]

    // merged converts (1 kernel)
    cvt_all_kernel<<<(CN1 + CN2 + CN3) / 256, 256, 0, stream>>>(
        x, w_qkv, w_proj, xb, wqkvb, wprojb);

    // qkv GEMM + bias + RoPE + QSCALE + scatter (2-deep prefetch pipeline, no-spill bounds)
    dim3 g1(M_TOK / 128, 3 * DIM / 128);
    gemm_qkv_kernel<<<g1, 256, 0, stream>>>(xb, wqkvb, b_qkv, qb, kb, (_Float16*)vtb);

    // attention partials (key-split x2), 8 waves x 32 q-rows, XCD-swizzled 1D grid
    attn_kernel<<<dim3(9 * 2 * BH), 512, 0, stream>>>(qb, kb, (const _Float16*)vtb,
                                                      (_Float16*)opart, lpart);

    // proj GEMM with fused combine+normalize
    gemm_proj_kernel<<<dim3(M_TOK / 64, DIM / 64), 256, 0, stream>>>(
        (const _Float16*)opart, lpart, wprojb, b_proj, out);
}

// Round 9
// 168.238 us; speedup vs baseline: 1.3458x; 1.3458x over previous
//
#include <hip/hip_runtime.h>

// Problem constants
#define BATCH 2
#define NSEQ 2304       // 48*48
#define DIM 768
#define HEADS 12
#define HD 64
#define M_TOK (BATCH * NSEQ)   // 4608
#define LDSP 72                // padded LDS row stride (bf16 elems) - proj kernel
#define KP 72                  // attn LDS row stride (elems) for K (bf16) and V^T (f16)
#define BH (BATCH * HEADS)     // 24
#define KT_HALF (NSEQ / 64 / 2) // 18 key-tiles per half
#define NKT (DIM / 64)          // 12 k-steps in qkv GEMM

typedef __attribute__((ext_vector_type(8))) short bf16x8;
typedef __attribute__((ext_vector_type(8))) short short8v;
typedef __attribute__((ext_vector_type(4))) float f32x4;
typedef __fp16 fp16x2 __attribute__((ext_vector_type(2)));
typedef _Float16 half4 __attribute__((ext_vector_type(4)));
typedef _Float16 half8 __attribute__((ext_vector_type(8)));

// softmax scale folded with log2(e): exp(x) = exp2(x * log2e)
#define QSCALE (0.125f * 1.44269504088896f)
#define LOG2_100_D16 0.41524101186092029f   // log2(100)/16

__device__ __forceinline__ short f2bf(float f) {
    union { float f; unsigned u; } v; v.f = f;
    unsigned r = v.u + 0x7fffu + ((v.u >> 16) & 1u);
    return (short)(r >> 16);
}

// ---------------- merged fp32 -> bf16 conversion for x, w_qkv, w_proj ----------------
#define CN1 (M_TOK * DIM / 4)        // 884736
#define CN2 (3 * DIM * DIM / 4)      // 442368
#define CN3 (DIM * DIM / 4)          // 147456
__global__ void cvt_all_kernel(const float* __restrict__ x, const float* __restrict__ wq,
                               const float* __restrict__ wp,
                               short* __restrict__ xb, short* __restrict__ wqb,
                               short* __restrict__ wpb) {
    int i = blockIdx.x * 256 + threadIdx.x;
    const float* src; short* dst; int j;
    if (i < CN1)              { src = x;  dst = xb;  j = i; }
    else if (i < CN1 + CN2)   { src = wq; dst = wqb; j = i - CN1; }
    else                      { src = wp; dst = wpb; j = i - CN1 - CN2; }
    float4 v = reinterpret_cast<const float4*>(src)[j];
    short4 o;
    o.x = f2bf(v.x); o.y = f2bf(v.y); o.z = f2bf(v.z); o.w = f2bf(v.w);
    reinterpret_cast<short4*>(dst)[j] = o;
}

// ---------------- qkv GEMM: 128x128 tile, global_load_lds staging, XOR-swizzled ----------------
// R9: reg-staging pipeline spilled twice (R7/R8: 220 MB scratch, VGPR pinned 88).
// Replace staging entirely with __builtin_amdgcn_global_load_lds width=16 (m151:
// direct-to-LDS 874 vs reg-staging 646 TF at this exact tile shape): no VGPR
// round-trip, no ds_writes, DMA in flight across the whole compute phase before the
// pre-barrier vmcnt(0) drain. gload_lds writes linearly (wave base + lane*16), so
// LDS is UNPADDED [128][64]; bank spread recovered by XOR swizzle applied on BOTH
// sides (rule #21): source block j = (lane&7)^(lane>>3) (lane-constant), read block
// p = (ks*4+quad)^(l16&7). LDS 73.7->64 KB.
__global__ __launch_bounds__(256) void gemm_qkv_kernel(
    const short* __restrict__ A,    // xb [4608,768]
    const short* __restrict__ Bt,   // wqkvb [2304,768]
    const float* __restrict__ bias, // [2304]
    short* __restrict__ qb, short* __restrict__ kbuf, _Float16* __restrict__ vtb)
{
    __shared__ __align__(16) short At[2][128 * 64];
    __shared__ __align__(16) short Bl[2][128 * 64];
    const int m0 = blockIdx.x * 128, n0 = blockIdx.y * 128;
    const int tid = threadIdx.x, lane = tid & 63, wave = tid >> 6;
    const int quad = lane >> 4, l16 = lane & 15;
    const int wm = (wave >> 1) * 64, wn = (wave & 1) * 64;
    f32x4 acc[4][4] = {};

    // staging: wave w issue i covers LDS rows (w*4+i)*8..+7 (512 shorts, linear).
    // lane l -> row offset lrow=l>>3, LDS block p=l&7 which must hold SOURCE block
    // j = p ^ (r&7) = (l&7)^(l>>3)  (r&7==lrow since row bases are multiples of 8).
    const int lrow = lane >> 3;
    const int jsw = (lane & 7) ^ lrow;
    const short* aBase = &A[(size_t)(m0 + wave * 32 + lrow) * DIM + jsw * 8];
    const short* bBase = &Bt[(size_t)(n0 + wave * 32 + lrow) * DIM + jsw * 8];

    auto stage = [&](int buf, int k0) {
#pragma unroll
        for (int i = 0; i < 4; ++i) {
            __builtin_amdgcn_global_load_lds(
                (const __attribute__((address_space(1))) unsigned int*)(aBase + k0 + i * 8 * DIM),
                (__attribute__((address_space(3))) unsigned int*)&At[buf][(wave * 4 + i) * 512],
                16, 0, 0);
            __builtin_amdgcn_global_load_lds(
                (const __attribute__((address_space(1))) unsigned int*)(bBase + k0 + i * 8 * DIM),
                (__attribute__((address_space(3))) unsigned int*)&Bl[buf][(wave * 4 + i) * 512],
                16, 0, 0);
        }
    };

    stage(0, 0);   // prologue: tile 0 in flight

    const int rx = l16 & 7;   // read-side swizzle key (R&7 == l16&7 for all frag rows)
    int cur = 0;
    for (int kt = 0; kt < NKT; ++kt) {
        __syncthreads();   // compiler drains vmcnt(0): buf[cur] complete, buf[cur^1] free
        if (kt + 1 < NKT) stage(cur ^ 1, (kt + 1) * 64);   // async DMA during compute
#pragma unroll
        for (int ks = 0; ks < 2; ++ks) {
            bf16x8 af[4], bf[4];
#pragma unroll
            for (int mt = 0; mt < 4; ++mt) {
                const int R = wm + mt * 16 + l16;
                af[mt] = *reinterpret_cast<const bf16x8*>(
                    &At[cur][R * 64 + (((ks * 4 + quad) ^ rx) * 8)]);
            }
#pragma unroll
            for (int nt = 0; nt < 4; ++nt) {
                const int R = wn + nt * 16 + l16;
                bf[nt] = *reinterpret_cast<const bf16x8*>(
                    &Bl[cur][R * 64 + (((ks * 4 + quad) ^ rx) * 8)]);
            }
#pragma unroll
            for (int mt = 0; mt < 4; ++mt)
#pragma unroll
                for (int nt = 0; nt < 4; ++nt)
                    acc[mt][nt] = __builtin_amdgcn_mfma_f32_16x16x32_bf16(af[mt], bf[nt], acc[mt][nt], 0, 0, 0);
        }
        cur ^= 1;
    }

    const int which = (n0 + wn) / DIM;          // 0=q 1=k 2=v (wave-uniform)
    const int head = ((n0 + wn) % DIM) / HD;
    const int b = m0 / NSEQ;
    const int tokb = m0 % NSEQ + wm;
    if (which == 2) {
#pragma unroll
        for (int mt = 0; mt < 4; ++mt)
#pragma unroll
            for (int nt = 0; nt < 4; ++nt) {
                const int n = n0 + wn + nt * 16 + l16;
                const int d = nt * 16 + l16;
                const float bi = bias[n];
                const int tok0 = tokb + mt * 16 + quad * 4;
                half4 hv;
                hv.x = (_Float16)(acc[mt][nt][0] + bi);
                hv.y = (_Float16)(acc[mt][nt][1] + bi);
                hv.z = (_Float16)(acc[mt][nt][2] + bi);
                hv.w = (_Float16)(acc[mt][nt][3] + bi);
                *reinterpret_cast<half4*>(&vtb[((size_t)(b * HEADS + head) * HD + d) * NSEQ + tok0]) = hv;
            }
    } else {
        // fused RoPE: pairs (d, d+32) = (nt, nt+2); pi = l16
        short* dst = (which == 0) ? qb : kbuf;
        const float qs = (which == 0) ? QSCALE : 1.0f;
        float bi[4];
#pragma unroll
        for (int nt = 0; nt < 4; ++nt) bi[nt] = bias[n0 + wn + nt * 16 + l16];
        const float invp = __builtin_amdgcn_exp2f(-(float)l16 * LOG2_100_D16); // 100^(-l16/16)
#pragma unroll
        for (int mt = 0; mt < 4; ++mt) {
#pragma unroll
            for (int rg = 0; rg < 4; ++rg) {
                const int tok = tokb + mt * 16 + quad * 4 + rg;
                const int yy = tok / 48, xx = tok - yy * 48;
                const float ry = (2.0f * (yy + 0.5f) * (1.0f / 48.0f) - 1.0f) * invp; // revolutions
                const float rx2 = (2.0f * (xx + 0.5f) * (1.0f / 48.0f) - 1.0f) * invp;
                const float sy = __builtin_amdgcn_sinf(ry), cy = __builtin_amdgcn_cosf(ry);
                const float sx = __builtin_amdgcn_sinf(rx2), cx = __builtin_amdgcn_cosf(rx2);
                const float a0 = acc[mt][0][rg] + bi[0];
                const float a1 = acc[mt][1][rg] + bi[1];
                const float a2 = acc[mt][2][rg] + bi[2];
                const float a3 = acc[mt][3][rg] + bi[3];
                short* rp = &dst[((size_t)(b * HEADS + head) * NSEQ + tok) * HD];
                rp[l16]      = f2bf((a0 * cy - a2 * sy) * qs);
                rp[32 + l16] = f2bf((a2 * cy + a0 * sy) * qs);
                rp[16 + l16] = f2bf((a1 * cx - a3 * sx) * qs);
                rp[48 + l16] = f2bf((a3 * cx + a1 * sx) * qs);
            }
        }
    }
}

// ---------------- flash attention: 8 waves x 32 q-rows, key-split x2, XCD-swizzled ----------------
// R6 structure (kept): <=128-reg tier -> 4 waves/SIMD; 512-thread blocks, 256 rows.
// K/V LDS layouts conflict-uniform b128 (R4).
__global__ __launch_bounds__(512, 4) void attn_kernel(
    const short* __restrict__ qb, const short* __restrict__ kb,
    const _Float16* __restrict__ vtb, _Float16* __restrict__ opart,
    float* __restrict__ lpart)
{
    __shared__ __align__(16) short    Kt[2][64 * KP];   // [key][d]        bf16
    __shared__ __align__(16) _Float16 Vt[2][64 * KP];   // [d][tok-perm]   f16
    const int wg = blockIdx.x;
    const int xcd = wg & 7;
    const int slot = wg >> 3;              // 0..53
    const int slab = xcd * 6 + slot / 9;   // 0..47 (all 9 q-tiles of a slab on one XCD)
    const int qt = slot % 9;
    const int kh = slab & 1;
    const int bh = slab >> 1;
    const int tid = threadIdx.x, lane = tid & 63, wave = tid >> 6;   // wave 0..7
    const int quad = lane >> 4, l16 = lane & 15;
    const int qrow0 = qt * 256 + wave * 32;
    const short* qbase = qb + (size_t)bh * NSEQ * HD;
    const short* kbase = kb + (size_t)bh * NSEQ * HD;
    const _Float16* vbase = vtb + (size_t)bh * HD * NSEQ;

    bf16x8 qf[2][2];
#pragma unroll
    for (int mt = 0; mt < 2; ++mt)
#pragma unroll
        for (int ks = 0; ks < 2; ++ks)
            qf[mt][ks] = *reinterpret_cast<const bf16x8*>(
                &qbase[(size_t)(qrow0 + mt * 16 + l16) * HD + ks * 32 + quad * 8]);

    half8 ones8;
#pragma unroll
    for (int j = 0; j < 8; ++j) ones8[j] = (_Float16)1.0f;

    f32x4 oacc[2][4] = {};
    f32x4 lacc[2] = {};

    // staging (512 threads, one uint4 each):
    //   K: row rk = tid>>3, 8 shorts at ck = (tid&7)*8
    //   V: d-row rv = tid>>3, 8 tokens T = 8*(tid&7); permuted dest
    //      p0 = 32*(w>>2) + 16*(w&1) + 4*((w>>1)&1)  [uint2 at p0, p0+8]
    const int rk = tid >> 3, ck = (tid & 7) * 8;
    const int wv = tid & 7;
    const int vdst = rk * KP + 32 * (wv >> 2) + 16 * (wv & 1) + 4 * ((wv >> 1) & 1);
    const int t0 = kh * (NSEQ / 2);
    const short* kp = kbase + (size_t)(t0 + rk) * HD + ck;
    const _Float16* vp = vbase + (size_t)rk * NSEQ + t0 + wv * 8;

    // prologue: stage first tile into buffer 0
    {
        uint4 k0 = *reinterpret_cast<const uint4*>(kp);
        uint4 v0 = *reinterpret_cast<const uint4*>(vp);
        *reinterpret_cast<uint4*>(&Kt[0][rk * KP + ck]) = k0;
        _Float16* vb = &Vt[0][vdst];
        *reinterpret_cast<uint2*>(vb + 0) = make_uint2(v0.x, v0.y);
        *reinterpret_cast<uint2*>(vb + 8) = make_uint2(v0.z, v0.w);
        kp += 64 * HD;
        vp += 64;
    }

    int cur = 0;
    for (int kt = 0; kt < KT_HALF; ++kt) {
        __syncthreads();   // buf[cur] visible; readers of buf[cur^1] done
        uint4 k0, v0;
        const bool pre = (kt + 1 < KT_HALF);
        if (pre) {   // issue next-tile loads; latency hides under this tile's compute
            k0 = *reinterpret_cast<const uint4*>(kp);
            v0 = *reinterpret_cast<const uint4*>(vp);
            kp += 64 * HD;
            vp += 64;
        }

        // hoist K and V^T fragments once, reuse over 2 m-tiles (all b128, conflict-uniform)
        bf16x8 kf[2][4];
#pragma unroll
        for (int ks = 0; ks < 2; ++ks)
#pragma unroll
            for (int nt = 0; nt < 4; ++nt)
                kf[ks][nt] = *reinterpret_cast<const bf16x8*>(
                    &Kt[cur][(nt * 16 + l16) * KP + ks * 32 + quad * 8]);
        half8 vf8[2][4];
#pragma unroll
        for (int n2 = 0; n2 < 2; ++n2)
#pragma unroll
            for (int dt = 0; dt < 4; ++dt)
                vf8[n2][dt] = *reinterpret_cast<const half8*>(
                    &Vt[cur][(dt * 16 + l16) * KP + 32 * n2 + 8 * quad]);

#pragma unroll
        for (int mt = 0; mt < 2; ++mt) {
            // S^T = K Q^T for this 16-row m-tile
            f32x4 sacc[4] = {};
#pragma unroll
            for (int ks = 0; ks < 2; ++ks)
#pragma unroll
                for (int nt = 0; nt < 4; ++nt)
                    sacc[nt] = __builtin_amdgcn_mfma_f32_16x16x32_bf16(
                        kf[ks][nt], qf[mt][ks], sacc[nt], 0, 0, 0);

            // P = exp2(S^T) -> K=32 f16 A-fragments (key-permuted, matches vf8)
            half8 pf8[2];
#pragma unroll
            for (int n2 = 0; n2 < 2; ++n2) {
                fp16x2 w0 = __builtin_amdgcn_cvt_pkrtz(
                    __builtin_amdgcn_exp2f(sacc[2 * n2][0]),
                    __builtin_amdgcn_exp2f(sacc[2 * n2][1]));
                fp16x2 w1 = __builtin_amdgcn_cvt_pkrtz(
                    __builtin_amdgcn_exp2f(sacc[2 * n2][2]),
                    __builtin_amdgcn_exp2f(sacc[2 * n2][3]));
                fp16x2 w2 = __builtin_amdgcn_cvt_pkrtz(
                    __builtin_amdgcn_exp2f(sacc[2 * n2 + 1][0]),
                    __builtin_amdgcn_exp2f(sacc[2 * n2 + 1][1]));
                fp16x2 w3 = __builtin_amdgcn_cvt_pkrtz(
                    __builtin_amdgcn_exp2f(sacc[2 * n2 + 1][2]),
                    __builtin_amdgcn_exp2f(sacc[2 * n2 + 1][3]));
                half8 p;
                p[0] = (_Float16)w0.x; p[1] = (_Float16)w0.y;
                p[2] = (_Float16)w1.x; p[3] = (_Float16)w1.y;
                p[4] = (_Float16)w2.x; p[5] = (_Float16)w2.y;
                p[6] = (_Float16)w3.x; p[7] = (_Float16)w3.y;
                pf8[n2] = p;
            }

            // l += P * ones ; O += P V   (K=32 f16 MFMAs)
#pragma unroll
            for (int n2 = 0; n2 < 2; ++n2)
                lacc[mt] = __builtin_amdgcn_mfma_f32_16x16x32_f16(
                    pf8[n2], ones8, lacc[mt], 0, 0, 0);
#pragma unroll
            for (int n2 = 0; n2 < 2; ++n2)
#pragma unroll
                for (int dt = 0; dt < 4; ++dt)
                    oacc[mt][dt] = __builtin_amdgcn_mfma_f32_16x16x32_f16(
                        pf8[n2], vf8[n2][dt], oacc[mt][dt], 0, 0, 0);
        }

        if (pre) {   // stage next tile; vmcnt wait lands after the tile's compute
            *reinterpret_cast<uint4*>(&Kt[cur ^ 1][rk * KP + ck]) = k0;
            _Float16* vb = &Vt[cur ^ 1][vdst];
            *reinterpret_cast<uint2*>(vb + 0) = make_uint2(v0.x, v0.y);
            *reinterpret_cast<uint2*>(vb + 8) = make_uint2(v0.z, v0.w);
        }
        cur ^= 1;
    }

    // store UNNORMALIZED partials
    _Float16* ob2 = opart + (size_t)(kh * BH + bh) * NSEQ * HD;
    float* lp2 = lpart + (size_t)(kh * BH + bh) * NSEQ;
#pragma unroll
    for (int mt = 0; mt < 2; ++mt) {
#pragma unroll
        for (int dt = 0; dt < 4; ++dt)
#pragma unroll
            for (int rg = 0; rg < 4; ++rg) {
                int row = qrow0 + mt * 16 + quad * 4 + rg;
                ob2[(size_t)row * HD + dt * 16 + l16] = (_Float16)oacc[mt][dt][rg];
            }
        if (l16 == 0) {
#pragma unroll
            for (int rg = 0; rg < 4; ++rg)
                lp2[qrow0 + mt * 16 + quad * 4 + rg] = lacc[mt][rg];
        }
    }
}

// ---------------- proj GEMM with fused softmax-combine ----------------
__global__ __launch_bounds__(256) void gemm_proj_kernel(
    const _Float16* __restrict__ op,  // [2][bh][row][d] f16 partials
    const float* __restrict__ lp,     // [2][bh][row] f32 partials
    const short* __restrict__ Bt,     // wprojb [768,768]
    const float* __restrict__ bias,   // [768]
    float* __restrict__ out)
{
    __shared__ __align__(16) short At[64 * LDSP];
    __shared__ __align__(16) short Bl[64 * LDSP];
    const int m0 = blockIdx.x * 64, n0 = blockIdx.y * 64;
    const int tid = threadIdx.x, lane = tid & 63, wave = tid >> 6;
    const int quad = lane >> 4, l16 = lane & 15;
    const int wm = (wave >> 1) * 32, wn = (wave & 1) * 32;
    const int r = tid >> 2, cs = (tid & 3) * 16;
    const int b = m0 / NSEQ;
    const int tok = m0 % NSEQ + r;
    f32x4 acc[2][2] = {};

    for (int k0 = 0; k0 < DIM; k0 += 64) {
        // fused combine: this k-tile is head h
        const int h = k0 >> 6;
        const size_t pb = (size_t)(b * HEADS + h) * NSEQ + tok;
        const float l0 = lp[pb], l1 = lp[(size_t)BH * NSEQ + pb];
        const float inv = __builtin_amdgcn_rcpf(l0 + l1);
        const half8* o0 = reinterpret_cast<const half8*>(&op[pb * HD + cs]);
        const half8* o1 = reinterpret_cast<const half8*>(&op[(size_t)BH * NSEQ * HD + pb * HD + cs]);
        half8 p0 = o0[0], p1 = o0[1], q0 = o1[0], q1 = o1[1];
        const uint4* gb = reinterpret_cast<const uint4*>(&Bt[(size_t)(n0 + r) * DIM + k0 + cs]);
        uint4 bw0 = gb[0], bw1 = gb[1];
        short8v s0, s1;
#pragma unroll
        for (int j = 0; j < 8; ++j) {
            s0[j] = f2bf(((float)p0[j] + (float)q0[j]) * inv);
            s1[j] = f2bf(((float)p1[j] + (float)q1[j]) * inv);
        }
        *reinterpret_cast<short8v*>(&At[r * LDSP + cs]) = s0;
        *reinterpret_cast<short8v*>(&At[r * LDSP + cs + 8]) = s1;
        uint4* sb = reinterpret_cast<uint4*>(&Bl[r * LDSP + cs]);
        sb[0] = bw0; sb[1] = bw1;
        __syncthreads();
#pragma unroll
        for (int ks = 0; ks < 2; ++ks) {
            bf16x8 af[2], bf[2];
#pragma unroll
            for (int mt = 0; mt < 2; ++mt)
                af[mt] = *reinterpret_cast<const bf16x8*>(&At[(wm + mt * 16 + l16) * LDSP + ks * 32 + quad * 8]);
#pragma unroll
            for (int nt = 0; nt < 2; ++nt)
                bf[nt] = *reinterpret_cast<const bf16x8*>(&Bl[(wn + nt * 16 + l16) * LDSP + ks * 32 + quad * 8]);
#pragma unroll
            for (int mt = 0; mt < 2; ++mt)
#pragma unroll
                for (int nt = 0; nt < 2; ++nt)
                    acc[mt][nt] = __builtin_amdgcn_mfma_f32_16x16x32_bf16(af[mt], bf[nt], acc[mt][nt], 0, 0, 0);
        }
        __syncthreads();
    }

#pragma unroll
    for (int mt = 0; mt < 2; ++mt)
#pragma unroll
        for (int nt = 0; nt < 2; ++nt) {
            const int n = n0 + wn + nt * 16 + l16;
            const float bi = bias[n];
#pragma unroll
            for (int rg = 0; rg < 4; ++rg) {
                const int m = m0 + wm + mt * 16 + quad * 4 + rg;
                out[(size_t)m * DIM + n] = acc[mt][nt][rg] + bi;
            }
        }
}

extern "C" void kernel_launch(void* const* d_in, const int* in_sizes, int n_in,
                              void* d_out, int out_size, void* d_ws, size_t ws_size,
                              hipStream_t stream) {
    const float* x      = (const float*)d_in[0];
    const float* w_qkv  = (const float*)d_in[1];
    const float* b_qkv  = (const float*)d_in[2];
    const float* w_proj = (const float*)d_in[3];
    const float* b_proj = (const float*)d_in[4];
    float* out = (float*)d_out;

    short* xb     = (short*)d_ws;                         // 4608*768
    short* wqkvb  = xb + (size_t)M_TOK * DIM;             // 2304*768
    short* wprojb = wqkvb + (size_t)3 * DIM * DIM;        // 768*768
    short* qb     = wprojb + (size_t)DIM * DIM;           // 24*2304*64 bf16
    short* kb     = qb + (size_t)BH * NSEQ * HD;
    short* vtb    = kb + (size_t)BH * NSEQ * HD;          // f16 [bh,d,tok]
    short* opart  = vtb + (size_t)BH * NSEQ * HD;         // f16 [2,bh,row,d]
    float* lpart  = (float*)(opart + (size_t)2 * BH * NSEQ * HD); // f32 [2,bh,row]

    // merged converts (1 kernel)
    cvt_all_kernel<<<(CN1 + CN2 + CN3) / 256, 256, 0, stream>>>(
        x, w_qkv, w_proj, xb, wqkvb, wprojb);

    // qkv GEMM + bias + RoPE + QSCALE + scatter (global_load_lds staging)
    dim3 g1(M_TOK / 128, 3 * DIM / 128);
    gemm_qkv_kernel<<<g1, 256, 0, stream>>>(xb, wqkvb, b_qkv, qb, kb, (_Float16*)vtb);

    // attention partials (key-split x2), 8 waves x 32 q-rows, XCD-swizzled 1D grid
    attn_kernel<<<dim3(9 * 2 * BH), 512, 0, stream>>>(qb, kb, (const _Float16*)vtb,
                                                      (_Float16*)opart, lpart);

    // proj GEMM with fused combine+normalize
    gemm_proj_kernel<<<dim3(M_TOK / 64, DIM / 64), 256, 0, stream>>>(
        (const _Float16*)opart, lpart, wprojb, b_proj, out);
}

// Round 10
// 163.527 us; speedup vs baseline: 1.3845x; 1.0288x over previous
//
#include <hip/hip_runtime.h>

// Problem constants
#define BATCH 2
#define NSEQ 2304       // 48*48
#define DIM 768
#define HEADS 12
#define HD 64
#define M_TOK (BATCH * NSEQ)   // 4608
#define LDSP 72                // padded LDS row stride (bf16 elems) - proj kernel
#define KP 72                  // attn LDS row stride (elems) for K (bf16) and V^T (f16)
#define BH (BATCH * HEADS)     // 24
#define KT_HALF (NSEQ / 64 / 2) // 18 key-tiles per half
#define NKT (DIM / 64)          // 12 k-steps in qkv GEMM

typedef __attribute__((ext_vector_type(8))) short bf16x8;
typedef __attribute__((ext_vector_type(8))) short short8v;
typedef __attribute__((ext_vector_type(4))) float f32x4;
typedef __fp16 fp16x2 __attribute__((ext_vector_type(2)));
typedef _Float16 half4 __attribute__((ext_vector_type(4)));
typedef _Float16 half8 __attribute__((ext_vector_type(8)));

// softmax scale folded with log2(e): exp(x) = exp2(x * log2e)
#define QSCALE (0.125f * 1.44269504088896f)
#define LOG2_100_D16 0.41524101186092029f   // log2(100)/16

__device__ __forceinline__ short f2bf(float f) {
    union { float f; unsigned u; } v; v.f = f;
    unsigned r = v.u + 0x7fffu + ((v.u >> 16) & 1u);
    return (short)(r >> 16);
}

// ---------------- merged fp32 -> bf16 conversion for x, w_qkv, w_proj ----------------
#define CN1 (M_TOK * DIM / 4)        // 884736
#define CN2 (3 * DIM * DIM / 4)      // 442368
#define CN3 (DIM * DIM / 4)          // 147456
__global__ void cvt_all_kernel(const float* __restrict__ x, const float* __restrict__ wq,
                               const float* __restrict__ wp,
                               short* __restrict__ xb, short* __restrict__ wqb,
                               short* __restrict__ wpb) {
    int i = blockIdx.x * 256 + threadIdx.x;
    const float* src; short* dst; int j;
    if (i < CN1)              { src = x;  dst = xb;  j = i; }
    else if (i < CN1 + CN2)   { src = wq; dst = wqb; j = i - CN1; }
    else                      { src = wp; dst = wpb; j = i - CN1 - CN2; }
    float4 v = reinterpret_cast<const float4*>(src)[j];
    short4 o;
    o.x = f2bf(v.x); o.y = f2bf(v.y); o.z = f2bf(v.z); o.w = f2bf(v.w);
    reinterpret_cast<short4*>(dst)[j] = o;
}

// ---------------- qkv GEMM: 128x128 tile, 8 waves, global_load_lds, XOR-swizzled ----------------
// R10: R6/R7/R8/R9 all plateau at ~50us with 4 waves/block (2 waves/SIMD) regardless
// of staging mechanism -> occupancy-trap, same as attn pre-R6. Fix mirrors R6:
// 512 threads (8 waves), per-wave output 32x64 (acc[2][4]=32 regs), same 128x128
// tile, same 64 KB LDS (2 blocks/CU) -> 16 waves/CU = 4 waves/SIMD, doubling TLP
// for the DMA/ds_read/MFMA chain. Staging stays global_load_lds (R9: 0 conflicts,
// no spill): wave w issues 2 At + 2 Bl row-octets, source pre-swizzled
// j=(lane&7)^(lane>>3), reads XOR the same key.
__global__ __launch_bounds__(512) void gemm_qkv_kernel(
    const short* __restrict__ A,    // xb [4608,768]
    const short* __restrict__ Bt,   // wqkvb [2304,768]
    const float* __restrict__ bias, // [2304]
    short* __restrict__ qb, short* __restrict__ kbuf, _Float16* __restrict__ vtb)
{
    __shared__ __align__(16) short At[2][128 * 64];
    __shared__ __align__(16) short Bl[2][128 * 64];
    const int m0 = blockIdx.x * 128, n0 = blockIdx.y * 128;
    const int tid = threadIdx.x, lane = tid & 63, wave = tid >> 6;   // 0..7
    const int quad = lane >> 4, l16 = lane & 15;
    const int wm = (wave >> 1) * 32, wn = (wave & 1) * 64;
    f32x4 acc[2][4] = {};

    // staging: wave w covers rows w*16..w*16+15 (2 issues x 8 rows each).
    // lane l -> row offset lrow=l>>3, LDS block p=l&7 holds source block
    // j = p ^ (row&7) = (l&7)^(l>>3).
    const int lrow = lane >> 3;
    const int jsw = (lane & 7) ^ lrow;
    const short* aBase = &A[(size_t)(m0 + wave * 16 + lrow) * DIM + jsw * 8];
    const short* bBase = &Bt[(size_t)(n0 + wave * 16 + lrow) * DIM + jsw * 8];

    auto stage = [&](int buf, int k0) {
#pragma unroll
        for (int i = 0; i < 2; ++i) {
            __builtin_amdgcn_global_load_lds(
                (const __attribute__((address_space(1))) unsigned int*)(aBase + k0 + i * 8 * DIM),
                (__attribute__((address_space(3))) unsigned int*)&At[buf][(wave * 2 + i) * 512],
                16, 0, 0);
            __builtin_amdgcn_global_load_lds(
                (const __attribute__((address_space(1))) unsigned int*)(bBase + k0 + i * 8 * DIM),
                (__attribute__((address_space(3))) unsigned int*)&Bl[buf][(wave * 2 + i) * 512],
                16, 0, 0);
        }
    };

    stage(0, 0);   // prologue: tile 0 in flight

    const int rx = l16 & 7;   // read-side swizzle key (row&7 == l16&7 for frag rows)
    int cur = 0;
    for (int kt = 0; kt < NKT; ++kt) {
        __syncthreads();   // compiler drains vmcnt(0): buf[cur] complete, buf[cur^1] free
        if (kt + 1 < NKT) stage(cur ^ 1, (kt + 1) * 64);   // async DMA during compute
#pragma unroll
        for (int ks = 0; ks < 2; ++ks) {
            bf16x8 af[2], bf[4];
#pragma unroll
            for (int mt = 0; mt < 2; ++mt) {
                const int R = wm + mt * 16 + l16;
                af[mt] = *reinterpret_cast<const bf16x8*>(
                    &At[cur][R * 64 + (((ks * 4 + quad) ^ rx) * 8)]);
            }
#pragma unroll
            for (int nt = 0; nt < 4; ++nt) {
                const int R = wn + nt * 16 + l16;
                bf[nt] = *reinterpret_cast<const bf16x8*>(
                    &Bl[cur][R * 64 + (((ks * 4 + quad) ^ rx) * 8)]);
            }
#pragma unroll
            for (int mt = 0; mt < 2; ++mt)
#pragma unroll
                for (int nt = 0; nt < 4; ++nt)
                    acc[mt][nt] = __builtin_amdgcn_mfma_f32_16x16x32_bf16(af[mt], bf[nt], acc[mt][nt], 0, 0, 0);
        }
        cur ^= 1;
    }

    const int which = (n0 + wn) / DIM;          // 0=q 1=k 2=v (wave-uniform)
    const int head = ((n0 + wn) % DIM) / HD;
    const int b = m0 / NSEQ;
    const int tokb = m0 % NSEQ + wm;
    if (which == 2) {
#pragma unroll
        for (int mt = 0; mt < 2; ++mt)
#pragma unroll
            for (int nt = 0; nt < 4; ++nt) {
                const int n = n0 + wn + nt * 16 + l16;
                const int d = nt * 16 + l16;
                const float bi = bias[n];
                const int tok0 = tokb + mt * 16 + quad * 4;
                half4 hv;
                hv.x = (_Float16)(acc[mt][nt][0] + bi);
                hv.y = (_Float16)(acc[mt][nt][1] + bi);
                hv.z = (_Float16)(acc[mt][nt][2] + bi);
                hv.w = (_Float16)(acc[mt][nt][3] + bi);
                *reinterpret_cast<half4*>(&vtb[((size_t)(b * HEADS + head) * HD + d) * NSEQ + tok0]) = hv;
            }
    } else {
        // fused RoPE: pairs (d, d+32) = (nt, nt+2); pi = l16
        short* dst = (which == 0) ? qb : kbuf;
        const float qs = (which == 0) ? QSCALE : 1.0f;
        float bi[4];
#pragma unroll
        for (int nt = 0; nt < 4; ++nt) bi[nt] = bias[n0 + wn + nt * 16 + l16];
        const float invp = __builtin_amdgcn_exp2f(-(float)l16 * LOG2_100_D16); // 100^(-l16/16)
#pragma unroll
        for (int mt = 0; mt < 2; ++mt) {
#pragma unroll
            for (int rg = 0; rg < 4; ++rg) {
                const int tok = tokb + mt * 16 + quad * 4 + rg;
                const int yy = tok / 48, xx = tok - yy * 48;
                const float ry = (2.0f * (yy + 0.5f) * (1.0f / 48.0f) - 1.0f) * invp; // revolutions
                const float rx2 = (2.0f * (xx + 0.5f) * (1.0f / 48.0f) - 1.0f) * invp;
                const float sy = __builtin_amdgcn_sinf(ry), cy = __builtin_amdgcn_cosf(ry);
                const float sx = __builtin_amdgcn_sinf(rx2), cx = __builtin_amdgcn_cosf(rx2);
                const float a0 = acc[mt][0][rg] + bi[0];
                const float a1 = acc[mt][1][rg] + bi[1];
                const float a2 = acc[mt][2][rg] + bi[2];
                const float a3 = acc[mt][3][rg] + bi[3];
                short* rp = &dst[((size_t)(b * HEADS + head) * NSEQ + tok) * HD];
                rp[l16]      = f2bf((a0 * cy - a2 * sy) * qs);
                rp[32 + l16] = f2bf((a2 * cy + a0 * sy) * qs);
                rp[16 + l16] = f2bf((a1 * cx - a3 * sx) * qs);
                rp[48 + l16] = f2bf((a3 * cx + a1 * sx) * qs);
            }
        }
    }
}

// ---------------- flash attention: 8 waves x 32 q-rows, key-split x2, XCD-swizzled ----------------
// R6 structure (kept): <=128-reg tier -> 4 waves/SIMD; 512-thread blocks, 256 rows.
// K/V LDS layouts conflict-uniform b128 (R4).
__global__ __launch_bounds__(512, 4) void attn_kernel(
    const short* __restrict__ qb, const short* __restrict__ kb,
    const _Float16* __restrict__ vtb, _Float16* __restrict__ opart,
    float* __restrict__ lpart)
{
    __shared__ __align__(16) short    Kt[2][64 * KP];   // [key][d]        bf16
    __shared__ __align__(16) _Float16 Vt[2][64 * KP];   // [d][tok-perm]   f16
    const int wg = blockIdx.x;
    const int xcd = wg & 7;
    const int slot = wg >> 3;              // 0..53
    const int slab = xcd * 6 + slot / 9;   // 0..47 (all 9 q-tiles of a slab on one XCD)
    const int qt = slot % 9;
    const int kh = slab & 1;
    const int bh = slab >> 1;
    const int tid = threadIdx.x, lane = tid & 63, wave = tid >> 6;   // wave 0..7
    const int quad = lane >> 4, l16 = lane & 15;
    const int qrow0 = qt * 256 + wave * 32;
    const short* qbase = qb + (size_t)bh * NSEQ * HD;
    const short* kbase = kb + (size_t)bh * NSEQ * HD;
    const _Float16* vbase = vtb + (size_t)bh * HD * NSEQ;

    bf16x8 qf[2][2];
#pragma unroll
    for (int mt = 0; mt < 2; ++mt)
#pragma unroll
        for (int ks = 0; ks < 2; ++ks)
            qf[mt][ks] = *reinterpret_cast<const bf16x8*>(
                &qbase[(size_t)(qrow0 + mt * 16 + l16) * HD + ks * 32 + quad * 8]);

    half8 ones8;
#pragma unroll
    for (int j = 0; j < 8; ++j) ones8[j] = (_Float16)1.0f;

    f32x4 oacc[2][4] = {};
    f32x4 lacc[2] = {};

    // staging (512 threads, one uint4 each):
    //   K: row rk = tid>>3, 8 shorts at ck = (tid&7)*8
    //   V: d-row rv = tid>>3, 8 tokens T = 8*(tid&7); permuted dest
    //      p0 = 32*(w>>2) + 16*(w&1) + 4*((w>>1)&1)  [uint2 at p0, p0+8]
    const int rk = tid >> 3, ck = (tid & 7) * 8;
    const int wv = tid & 7;
    const int vdst = rk * KP + 32 * (wv >> 2) + 16 * (wv & 1) + 4 * ((wv >> 1) & 1);
    const int t0 = kh * (NSEQ / 2);
    const short* kp = kbase + (size_t)(t0 + rk) * HD + ck;
    const _Float16* vp = vbase + (size_t)rk * NSEQ + t0 + wv * 8;

    // prologue: stage first tile into buffer 0
    {
        uint4 k0 = *reinterpret_cast<const uint4*>(kp);
        uint4 v0 = *reinterpret_cast<const uint4*>(vp);
        *reinterpret_cast<uint4*>(&Kt[0][rk * KP + ck]) = k0;
        _Float16* vb = &Vt[0][vdst];
        *reinterpret_cast<uint2*>(vb + 0) = make_uint2(v0.x, v0.y);
        *reinterpret_cast<uint2*>(vb + 8) = make_uint2(v0.z, v0.w);
        kp += 64 * HD;
        vp += 64;
    }

    int cur = 0;
    for (int kt = 0; kt < KT_HALF; ++kt) {
        __syncthreads();   // buf[cur] visible; readers of buf[cur^1] done
        uint4 k0, v0;
        const bool pre = (kt + 1 < KT_HALF);
        if (pre) {   // issue next-tile loads; latency hides under this tile's compute
            k0 = *reinterpret_cast<const uint4*>(kp);
            v0 = *reinterpret_cast<const uint4*>(vp);
            kp += 64 * HD;
            vp += 64;
        }

        // hoist K and V^T fragments once, reuse over 2 m-tiles (all b128, conflict-uniform)
        bf16x8 kf[2][4];
#pragma unroll
        for (int ks = 0; ks < 2; ++ks)
#pragma unroll
            for (int nt = 0; nt < 4; ++nt)
                kf[ks][nt] = *reinterpret_cast<const bf16x8*>(
                    &Kt[cur][(nt * 16 + l16) * KP + ks * 32 + quad * 8]);
        half8 vf8[2][4];
#pragma unroll
        for (int n2 = 0; n2 < 2; ++n2)
#pragma unroll
            for (int dt = 0; dt < 4; ++dt)
                vf8[n2][dt] = *reinterpret_cast<const half8*>(
                    &Vt[cur][(dt * 16 + l16) * KP + 32 * n2 + 8 * quad]);

#pragma unroll
        for (int mt = 0; mt < 2; ++mt) {
            // S^T = K Q^T for this 16-row m-tile
            f32x4 sacc[4] = {};
#pragma unroll
            for (int ks = 0; ks < 2; ++ks)
#pragma unroll
                for (int nt = 0; nt < 4; ++nt)
                    sacc[nt] = __builtin_amdgcn_mfma_f32_16x16x32_bf16(
                        kf[ks][nt], qf[mt][ks], sacc[nt], 0, 0, 0);

            // P = exp2(S^T) -> K=32 f16 A-fragments (key-permuted, matches vf8)
            half8 pf8[2];
#pragma unroll
            for (int n2 = 0; n2 < 2; ++n2) {
                fp16x2 w0 = __builtin_amdgcn_cvt_pkrtz(
                    __builtin_amdgcn_exp2f(sacc[2 * n2][0]),
                    __builtin_amdgcn_exp2f(sacc[2 * n2][1]));
                fp16x2 w1 = __builtin_amdgcn_cvt_pkrtz(
                    __builtin_amdgcn_exp2f(sacc[2 * n2][2]),
                    __builtin_amdgcn_exp2f(sacc[2 * n2][3]));
                fp16x2 w2 = __builtin_amdgcn_cvt_pkrtz(
                    __builtin_amdgcn_exp2f(sacc[2 * n2 + 1][0]),
                    __builtin_amdgcn_exp2f(sacc[2 * n2 + 1][1]));
                fp16x2 w3 = __builtin_amdgcn_cvt_pkrtz(
                    __builtin_amdgcn_exp2f(sacc[2 * n2 + 1][2]),
                    __builtin_amdgcn_exp2f(sacc[2 * n2 + 1][3]));
                half8 p;
                p[0] = (_Float16)w0.x; p[1] = (_Float16)w0.y;
                p[2] = (_Float16)w1.x; p[3] = (_Float16)w1.y;
                p[4] = (_Float16)w2.x; p[5] = (_Float16)w2.y;
                p[6] = (_Float16)w3.x; p[7] = (_Float16)w3.y;
                pf8[n2] = p;
            }

            // l += P * ones ; O += P V   (K=32 f16 MFMAs)
#pragma unroll
            for (int n2 = 0; n2 < 2; ++n2)
                lacc[mt] = __builtin_amdgcn_mfma_f32_16x16x32_f16(
                    pf8[n2], ones8, lacc[mt], 0, 0, 0);
#pragma unroll
            for (int n2 = 0; n2 < 2; ++n2)
#pragma unroll
                for (int dt = 0; dt < 4; ++dt)
                    oacc[mt][dt] = __builtin_amdgcn_mfma_f32_16x16x32_f16(
                        pf8[n2], vf8[n2][dt], oacc[mt][dt], 0, 0, 0);
        }

        if (pre) {   // stage next tile; vmcnt wait lands after the tile's compute
            *reinterpret_cast<uint4*>(&Kt[cur ^ 1][rk * KP + ck]) = k0;
            _Float16* vb = &Vt[cur ^ 1][vdst];
            *reinterpret_cast<uint2*>(vb + 0) = make_uint2(v0.x, v0.y);
            *reinterpret_cast<uint2*>(vb + 8) = make_uint2(v0.z, v0.w);
        }
        cur ^= 1;
    }

    // store UNNORMALIZED partials
    _Float16* ob2 = opart + (size_t)(kh * BH + bh) * NSEQ * HD;
    float* lp2 = lpart + (size_t)(kh * BH + bh) * NSEQ;
#pragma unroll
    for (int mt = 0; mt < 2; ++mt) {
#pragma unroll
        for (int dt = 0; dt < 4; ++dt)
#pragma unroll
            for (int rg = 0; rg < 4; ++rg) {
                int row = qrow0 + mt * 16 + quad * 4 + rg;
                ob2[(size_t)row * HD + dt * 16 + l16] = (_Float16)oacc[mt][dt][rg];
            }
        if (l16 == 0) {
#pragma unroll
            for (int rg = 0; rg < 4; ++rg)
                lp2[qrow0 + mt * 16 + quad * 4 + rg] = lacc[mt][rg];
        }
    }
}

// ---------------- proj GEMM with fused softmax-combine ----------------
__global__ __launch_bounds__(256) void gemm_proj_kernel(
    const _Float16* __restrict__ op,  // [2][bh][row][d] f16 partials
    const float* __restrict__ lp,     // [2][bh][row] f32 partials
    const short* __restrict__ Bt,     // wprojb [768,768]
    const float* __restrict__ bias,   // [768]
    float* __restrict__ out)
{
    __shared__ __align__(16) short At[64 * LDSP];
    __shared__ __align__(16) short Bl[64 * LDSP];
    const int m0 = blockIdx.x * 64, n0 = blockIdx.y * 64;
    const int tid = threadIdx.x, lane = tid & 63, wave = tid >> 6;
    const int quad = lane >> 4, l16 = lane & 15;
    const int wm = (wave >> 1) * 32, wn = (wave & 1) * 32;
    const int r = tid >> 2, cs = (tid & 3) * 16;
    const int b = m0 / NSEQ;
    const int tok = m0 % NSEQ + r;
    f32x4 acc[2][2] = {};

    for (int k0 = 0; k0 < DIM; k0 += 64) {
        // fused combine: this k-tile is head h
        const int h = k0 >> 6;
        const size_t pb = (size_t)(b * HEADS + h) * NSEQ + tok;
        const float l0 = lp[pb], l1 = lp[(size_t)BH * NSEQ + pb];
        const float inv = __builtin_amdgcn_rcpf(l0 + l1);
        const half8* o0 = reinterpret_cast<const half8*>(&op[pb * HD + cs]);
        const half8* o1 = reinterpret_cast<const half8*>(&op[(size_t)BH * NSEQ * HD + pb * HD + cs]);
        half8 p0 = o0[0], p1 = o0[1], q0 = o1[0], q1 = o1[1];
        const uint4* gb = reinterpret_cast<const uint4*>(&Bt[(size_t)(n0 + r) * DIM + k0 + cs]);
        uint4 bw0 = gb[0], bw1 = gb[1];
        short8v s0, s1;
#pragma unroll
        for (int j = 0; j < 8; ++j) {
            s0[j] = f2bf(((float)p0[j] + (float)q0[j]) * inv);
            s1[j] = f2bf(((float)p1[j] + (float)q1[j]) * inv);
        }
        *reinterpret_cast<short8v*>(&At[r * LDSP + cs]) = s0;
        *reinterpret_cast<short8v*>(&At[r * LDSP + cs + 8]) = s1;
        uint4* sb = reinterpret_cast<uint4*>(&Bl[r * LDSP + cs]);
        sb[0] = bw0; sb[1] = bw1;
        __syncthreads();
#pragma unroll
        for (int ks = 0; ks < 2; ++ks) {
            bf16x8 af[2], bf[2];
#pragma unroll
            for (int mt = 0; mt < 2; ++mt)
                af[mt] = *reinterpret_cast<const bf16x8*>(&At[(wm + mt * 16 + l16) * LDSP + ks * 32 + quad * 8]);
#pragma unroll
            for (int nt = 0; nt < 2; ++nt)
                bf[nt] = *reinterpret_cast<const bf16x8*>(&Bl[(wn + nt * 16 + l16) * LDSP + ks * 32 + quad * 8]);
#pragma unroll
            for (int mt = 0; mt < 2; ++mt)
#pragma unroll
                for (int nt = 0; nt < 2; ++nt)
                    acc[mt][nt] = __builtin_amdgcn_mfma_f32_16x16x32_bf16(af[mt], bf[nt], acc[mt][nt], 0, 0, 0);
        }
        __syncthreads();
    }

#pragma unroll
    for (int mt = 0; mt < 2; ++mt)
#pragma unroll
        for (int nt = 0; nt < 2; ++nt) {
            const int n = n0 + wn + nt * 16 + l16;
            const float bi = bias[n];
#pragma unroll
            for (int rg = 0; rg < 4; ++rg) {
                const int m = m0 + wm + mt * 16 + quad * 4 + rg;
                out[(size_t)m * DIM + n] = acc[mt][nt][rg] + bi;
            }
        }
}

extern "C" void kernel_launch(void* const* d_in, const int* in_sizes, int n_in,
                              void* d_out, int out_size, void* d_ws, size_t ws_size,
                              hipStream_t stream) {
    const float* x      = (const float*)d_in[0];
    const float* w_qkv  = (const float*)d_in[1];
    const float* b_qkv  = (const float*)d_in[2];
    const float* w_proj = (const float*)d_in[3];
    const float* b_proj = (const float*)d_in[4];
    float* out = (float*)d_out;

    short* xb     = (short*)d_ws;                         // 4608*768
    short* wqkvb  = xb + (size_t)M_TOK * DIM;             // 2304*768
    short* wprojb = wqkvb + (size_t)3 * DIM * DIM;        // 768*768
    short* qb     = wprojb + (size_t)DIM * DIM;           // 24*2304*64 bf16
    short* kb     = qb + (size_t)BH * NSEQ * HD;
    short* vtb    = kb + (size_t)BH * NSEQ * HD;          // f16 [bh,d,tok]
    short* opart  = vtb + (size_t)BH * NSEQ * HD;         // f16 [2,bh,row,d]
    float* lpart  = (float*)(opart + (size_t)2 * BH * NSEQ * HD); // f32 [2,bh,row]

    // merged converts (1 kernel)
    cvt_all_kernel<<<(CN1 + CN2 + CN3) / 256, 256, 0, stream>>>(
        x, w_qkv, w_proj, xb, wqkvb, wprojb);

    // qkv GEMM + bias + RoPE + QSCALE + scatter (8 waves, global_load_lds staging)
    dim3 g1(M_TOK / 128, 3 * DIM / 128);
    gemm_qkv_kernel<<<g1, 512, 0, stream>>>(xb, wqkvb, b_qkv, qb, kb, (_Float16*)vtb);

    // attention partials (key-split x2), 8 waves x 32 q-rows, XCD-swizzled 1D grid
    attn_kernel<<<dim3(9 * 2 * BH), 512, 0, stream>>>(qb, kb, (const _Float16*)vtb,
                                                      (_Float16*)opart, lpart);

    // proj GEMM with fused combine+normalize
    gemm_proj_kernel<<<dim3(M_TOK / 64, DIM / 64), 256, 0, stream>>>(
        (const _Float16*)opart, lpart, wprojb, b_proj, out);
}